// Round 12
// baseline (1070.120 us; speedup 1.0000x reference)
//
#include <hip/hip_runtime.h>
#include <stddef.h>
#include <stdint.h>

#define N_NODES 50000
#define N_EDGES 800000
#define NF 96
#define FE 64
#define DIN 256
#define DOUT 192
#define BN_EPS 1e-5f
#define NTILES (N_EDGES / 64)

typedef float f32x4 __attribute__((ext_vector_type(4)));
typedef short bf16x8 __attribute__((ext_vector_type(8)));

__device__ __forceinline__ unsigned short f2bf(float f) {
  unsigned int u = __float_as_uint(f);
  return (unsigned short)((u + 0x7fffu + ((u >> 16) & 1u)) >> 16);
}
__device__ __forceinline__ float sigmoidf_(float x) {
  return 1.f / (1.f + __expf(-x));
}
__device__ __forceinline__ float softplusf_(float x) {
  float t = exp2f(-fabsf(x) * 1.44269504f);
  return fmaxf(x, 0.f) + 0.69314718f * log2f(1.f + t);
}

// row permutation: A-row r holds sorted-edge e0 + rperm_(r); swaps rf<->hi so a
// thread's 16 C-fragment values are 16 CONSECUTIVE sorted edges.
__device__ __forceinline__ int rperm_(int r) {
  return ((r >> 2) & 3) * 16 + (r >> 4) * 4 + (r & 3);
}

// our col c' = cblk*16+lm -> orig col: cblk even -> gate (cblk/2)*16+lm ;
// cblk odd -> conv 96+(cblk/2)*16+lm  (gate/conv paired in-lane per wave)
__device__ __forceinline__ int col_perm(int c) {
  int t = c >> 4, lm = c & 15;
  return (t >> 1) * 16 + (t & 1) * 96 + lm;
}

// ---------------- conversion / sort kernels ----------------
__global__ void k_cvt(const float* __restrict__ in, unsigned short* __restrict__ out, int n4) {
  int stride = gridDim.x * blockDim.x;
  for (int i = blockIdx.x * blockDim.x + threadIdx.x; i < n4; i += stride) {
    float4 v = reinterpret_cast<const float4*>(in)[i];
    ushort4 o;
    o.x = f2bf(v.x); o.y = f2bf(v.y); o.z = f2bf(v.z); o.w = f2bf(v.w);
    reinterpret_cast<ushort4*>(out)[i] = o;
  }
}

// edge features converted INTO SORTED ORDER: ebs[p] = bf16(edge[perm[p]])
__global__ void k_cvt_es(const float* __restrict__ edge, const int* __restrict__ perm,
                         unsigned short* __restrict__ ebs) {
  int stride = gridDim.x * blockDim.x;
  for (int i = blockIdx.x * blockDim.x + threadIdx.x; i < N_EDGES * 16; i += stride) {
    int p = i >> 4, c = i & 15;
    int e = perm[p];
    float4 v = reinterpret_cast<const float4*>(edge + (size_t)e * FE)[c];
    ushort4 o;
    o.x = f2bf(v.x); o.y = f2bf(v.y); o.z = f2bf(v.z); o.w = f2bf(v.w);
    reinterpret_cast<ushort4*>(ebs + (size_t)p * FE)[c] = o;
  }
}

__global__ void k_cvt_w(const float* __restrict__ W, unsigned short* __restrict__ Wt) {
  int i = blockIdx.x * blockDim.x + threadIdx.x;
  if (i < DOUT * DIN) {
    int c = i / DIN, k = i % DIN;
    Wt[i] = f2bf(W[k * DOUT + col_perm(c)]);
  }
}

__global__ void k_hist(const int* __restrict__ idx1, int* __restrict__ icounts) {
  int stride = gridDim.x * blockDim.x;
  for (int e = blockIdx.x * blockDim.x + threadIdx.x; e < N_EDGES; e += stride)
    atomicAdd(&icounts[idx1[e]], 1);
}

// ---- 3-phase multi-block exclusive scan of icounts[50000] -> offsets ----
#define SCAN_B 512
#define SCAN_NB 98
__global__ void k_scanA(const int* __restrict__ ic, int* __restrict__ off,
                        int* __restrict__ bsum) {
  __shared__ int tmp[SCAN_B];
  int tid = threadIdx.x, i = blockIdx.x * SCAN_B + tid;
  int v = (i < N_NODES) ? ic[i] : 0;
  tmp[tid] = v;
  __syncthreads();
  for (int o = 1; o < SCAN_B; o <<= 1) {
    int t = (tid >= o) ? tmp[tid - o] : 0;
    __syncthreads();
    tmp[tid] += t;
    __syncthreads();
  }
  if (i < N_NODES) off[i] = tmp[tid] - v;
  if (tid == SCAN_B - 1) bsum[blockIdx.x] = tmp[tid];
}
__global__ void k_scanB(const int* __restrict__ bsum, int* __restrict__ boff) {
  __shared__ int tmp[128];
  int tid = threadIdx.x;
  int v = (tid < SCAN_NB) ? bsum[tid] : 0;
  tmp[tid] = v;
  __syncthreads();
  for (int o = 1; o < 128; o <<= 1) {
    int t = (tid >= o) ? tmp[tid - o] : 0;
    __syncthreads();
    tmp[tid] += t;
    __syncthreads();
  }
  if (tid < SCAN_NB) boff[tid] = tmp[tid] - v;
}
__global__ void k_scanC(int* __restrict__ off, const int* __restrict__ boff) {
  int i = blockIdx.x * SCAN_B + threadIdx.x;
  if (i < N_NODES) off[i] += boff[blockIdx.x];
}

// scatter edge ids into sorted-by-idx1 order; also pre-gather idx2
__global__ void k_perm(const int* __restrict__ idx1, const int* __restrict__ idx2,
                       const int* __restrict__ offsets, int* __restrict__ cursor,
                       int* __restrict__ perm, int* __restrict__ i1s,
                       int* __restrict__ i2s) {
  int stride = gridDim.x * blockDim.x;
  for (int e = blockIdx.x * blockDim.x + threadIdx.x; e < N_EDGES; e += stride) {
    int n = idx1[e];
    int p = offsets[n] + atomicAdd(&cursor[n], 1);
    perm[p] = e;
    i1s[p] = n;
    i2s[p] = idx2[e];
  }
}

// ---------------- shared GEMM machinery (R11 core) ----------------
#define GEMM_PROLOGUE()                                                        \
  const int tid = threadIdx.x;                                                 \
  const int lane = tid & 63;                                                   \
  const int w = tid >> 6;                                                      \
  const int lm = lane & 15;                                                    \
  const int hi = lane >> 4;                                                    \
  const int base_c = w * 32;                                                   \
  bf16x8 breg[2][8];                                                           \
  _Pragma("unroll") for (int ct = 0; ct < 2; ++ct)                             \
  _Pragma("unroll") for (int ks = 0; ks < 8; ++ks)                             \
      breg[ct][ks] = *reinterpret_cast<const bf16x8*>(                         \
          Wt + (size_t)(base_c + ct * 16 + lm) * DIN + ks * 32 + hi * 8);      \
  uint4 sv[6];

#define LOAD_TILE(T)                                                           \
  {                                                                            \
    const int e0_ = (T) * 64;                                                  \
    _Pragma("unroll") for (int k = 0; k < 6; ++k) {                            \
      int i = tid + k * 384;                                                   \
      if (i < 2048) {                                                          \
        int r = i >> 5, cs = i & 31;                                           \
        int es = e0_ + rperm_(r);                                              \
        int i1 = i1s[es];                                                      \
        int i2 = i2s[es];                                                      \
        const unsigned short* s0 = nb + (size_t)i1 * NF + cs * 8;              \
        const unsigned short* s1 = nb + (size_t)i2 * NF + (cs - 12) * 8;       \
        const unsigned short* s2 = ebs + (size_t)es * FE + (cs - 24) * 8;      \
        const unsigned short* src = cs < 12 ? s0 : (cs < 24 ? s1 : s2);        \
        sv[k] = *reinterpret_cast<const uint4*>(src);                          \
      }                                                                        \
    }                                                                          \
  }

#define WRITE_TILE(P)                                                          \
  _Pragma("unroll") for (int k = 0; k < 6; ++k) {                              \
    int i = tid + k * 384;                                                     \
    if (i < 2048) {                                                            \
      int r = i >> 5, cs = i & 31;                                             \
      *reinterpret_cast<uint4*>(&As[P][r * 256 + ((cs ^ (r & 7)) * 8)]) = sv[k]; \
    }                                                                          \
  }

#define COMPUTE_TILE(P)                                                        \
  _Pragma("unroll") for (int ks = 0; ks < 8; ++ks) {                           \
    bf16x8 a[4];                                                               \
    _Pragma("unroll") for (int rf = 0; rf < 4; ++rf) {                         \
      int row = rf * 16 + lm;                                                  \
      int slot = (ks * 4 + hi) ^ (lm & 7);                                     \
      a[rf] = *reinterpret_cast<const bf16x8*>(&As[P][row * 256 + slot * 8]);  \
    }                                                                          \
    _Pragma("unroll") for (int rf = 0; rf < 4; ++rf)                           \
      _Pragma("unroll") for (int ct = 0; ct < 2; ++ct)                         \
        acc[rf][ct] = __builtin_amdgcn_mfma_f32_16x16x32_bf16(                 \
            a[rf], breg[ct][ks], acc[rf][ct], 0, 0, 0);                        \
  }

// PASS 0 (big-ws): stats AND store packed y pairs (gate|conv) per sorted edge
__global__ __launch_bounds__(384, 3) void k_gy(
    const unsigned short* __restrict__ nb, const unsigned short* __restrict__ ebs,
    const unsigned short* __restrict__ Wt, const int* __restrict__ i1s,
    const int* __restrict__ i2s, unsigned int* __restrict__ yp,
    float* __restrict__ colsum, float* __restrict__ colsumsq) {
  __shared__ unsigned short As[2][64 * 256];  // 64 KB
  GEMM_PROLOGUE();
  float s1a[2] = {0.f, 0.f}, s2a[2] = {0.f, 0.f};

  int tile = blockIdx.x;
  int p = 0;
  if (tile < NTILES) LOAD_TILE(tile);
  for (; tile < NTILES; tile += gridDim.x) {
    const int e0 = tile * 64;
    WRITE_TILE(p);
    __syncthreads();
    int nt = tile + gridDim.x;
    if (nt < NTILES) LOAD_TILE(nt);

    f32x4 acc[4][2];
#pragma unroll
    for (int rf = 0; rf < 4; ++rf)
#pragma unroll
      for (int ct = 0; ct < 2; ++ct) acc[rf][ct] = (f32x4)(0.f);
    COMPUTE_TILE(p);

    // stats + pack/store: edges e0+hi*16+k (k = rf*4+j), col-pair mcol
    const int mcol = w * 16 + lm;
    unsigned int pk[16];
#pragma unroll
    for (int rf = 0; rf < 4; ++rf)
#pragma unroll
      for (int j = 0; j < 4; ++j) {
        float yg = acc[rf][0][j];
        float yc = acc[rf][1][j];
        s1a[0] += yg; s2a[0] += yg * yg;
        s1a[1] += yc; s2a[1] += yc * yc;
        pk[rf * 4 + j] = (unsigned int)f2bf(yg) | ((unsigned int)f2bf(yc) << 16);
      }
    unsigned int* dst = yp + (size_t)mcol * N_EDGES + e0 + hi * 16;
#pragma unroll
    for (int q = 0; q < 4; ++q)
      reinterpret_cast<uint4*>(dst)[q] =
          make_uint4(pk[q * 4], pk[q * 4 + 1], pk[q * 4 + 2], pk[q * 4 + 3]);
    p ^= 1;
  }

#pragma unroll
  for (int ct = 0; ct < 2; ++ct) {
    float s1 = s1a[ct], s2 = s2a[ct];
    s1 += __shfl_xor(s1, 16); s2 += __shfl_xor(s2, 16);
    s1 += __shfl_xor(s1, 32); s2 += __shfl_xor(s2, 32);
    if (lane < 16) {
      atomicAdd(&colsum[base_c + ct * 16 + lane], s1);
      atomicAdd(&colsumsq[base_c + ct * 16 + lane], s2);
    }
  }
}

// PASS 0 (fallback): stats only
__global__ __launch_bounds__(384, 3) void k_gstats(
    const unsigned short* __restrict__ nb, const unsigned short* __restrict__ ebs,
    const unsigned short* __restrict__ Wt, const int* __restrict__ i1s,
    const int* __restrict__ i2s, float* __restrict__ colsum,
    float* __restrict__ colsumsq) {
  __shared__ unsigned short As[2][64 * 256];
  GEMM_PROLOGUE();
  float s1a[2] = {0.f, 0.f}, s2a[2] = {0.f, 0.f};

  int tile = blockIdx.x;
  int p = 0;
  if (tile < NTILES) LOAD_TILE(tile);
  for (; tile < NTILES; tile += gridDim.x) {
    WRITE_TILE(p);
    __syncthreads();
    int nt = tile + gridDim.x;
    if (nt < NTILES) LOAD_TILE(nt);

    f32x4 acc[4][2];
#pragma unroll
    for (int rf = 0; rf < 4; ++rf)
#pragma unroll
      for (int ct = 0; ct < 2; ++ct) acc[rf][ct] = (f32x4)(0.f);
    COMPUTE_TILE(p);

#pragma unroll
    for (int ct = 0; ct < 2; ++ct)
#pragma unroll
      for (int rf = 0; rf < 4; ++rf)
#pragma unroll
        for (int j = 0; j < 4; ++j) {
          float y = acc[rf][ct][j];
          s1a[ct] += y;
          s2a[ct] += y * y;
        }
    p ^= 1;
  }

#pragma unroll
  for (int ct = 0; ct < 2; ++ct) {
    float s1 = s1a[ct], s2 = s2a[ct];
    s1 += __shfl_xor(s1, 16); s2 += __shfl_xor(s2, 16);
    s1 += __shfl_xor(s1, 32); s2 += __shfl_xor(s2, 32);
    if (lane < 16) {
      atomicAdd(&colsum[base_c + ct * 16 + lane], s1);
      atomicAdd(&colsumsq[base_c + ct * 16 + lane], s2);
    }
  }
}

// PASS 1 (fallback): full GEMM + in-register segmented scatter (R11)
__global__ __launch_bounds__(384, 3) void k_gmsg2(
    const unsigned short* __restrict__ nb, const unsigned short* __restrict__ ebs,
    const unsigned short* __restrict__ Wt, const int* __restrict__ i1s,
    const int* __restrict__ i2s, const float* __restrict__ a1,
    const float* __restrict__ b1f, float* __restrict__ sums) {
  __shared__ unsigned short As[2][64 * 256];
  GEMM_PROLOGUE();
  float c0[2], c1[2];
#pragma unroll
  for (int ct = 0; ct < 2; ++ct) {
    c0[ct] = a1[base_c + ct * 16 + lm];
    c1[ct] = b1f[base_c + ct * 16 + lm];
  }

  int tile = blockIdx.x;
  int p = 0;
  if (tile < NTILES) LOAD_TILE(tile);
  for (; tile < NTILES; tile += gridDim.x) {
    const int e0 = tile * 64;
    WRITE_TILE(p);
    __syncthreads();
    int nt = tile + gridDim.x;
    if (nt < NTILES) LOAD_TILE(nt);

    f32x4 acc[4][2];
#pragma unroll
    for (int rf = 0; rf < 4; ++rf)
#pragma unroll
      for (int ct = 0; ct < 2; ++ct) acc[rf][ct] = (f32x4)(0.f);
    COMPUTE_TILE(p);

    const int4* ip = reinterpret_cast<const int4*>(&i1s[e0 + hi * 16]);
    int4 n0 = ip[0], n1 = ip[1], n2 = ip[2], n3 = ip[3];
    int nidv[16] = {n0.x, n0.y, n0.z, n0.w, n1.x, n1.y, n1.z, n1.w,
                    n2.x, n2.y, n2.z, n2.w, n3.x, n3.y, n3.z, n3.w};

    const int mcol = w * 16 + lm;
    float run = 0.f;
    int curn = nidv[0];
#pragma unroll
    for (int rf = 0; rf < 4; ++rf)
#pragma unroll
      for (int j = 0; j < 4; ++j) {
        int k = rf * 4 + j;
        float zg = acc[rf][0][j] * c0[0] + c1[0];
        float zc = acc[rf][1][j] * c0[1] + c1[1];
        run += sigmoidf_(zg) * softplusf_(zc);
        int nxt = (k < 15) ? nidv[(k + 1) & 15] : -1;
        if (nxt != curn) {
          atomicAdd(&sums[(size_t)curn * NF + mcol], run);
          run = 0.f;
          curn = nxt;
        }
      }
    p ^= 1;
  }
}

// PASS 1 (big-ws): streaming read of ypair + affine + msg + segmented scatter
#define EPB 640  // edges per block (40 groups of 16); 800000/640 = 1250 blocks
__global__ __launch_bounds__(256) void k_msg(
    const unsigned int* __restrict__ yp, const int* __restrict__ i1s,
    const float* __restrict__ a1g, const float* __restrict__ b1g,
    const float* __restrict__ a1c, const float* __restrict__ b1c,
    float* __restrict__ sums) {
  __shared__ int nl[EPB];
  __shared__ float cg[96], dg[96], cc[96], dc[96];
  const int tid = threadIdx.x;
  const int e0 = blockIdx.x * EPB;
  for (int i = tid; i < EPB; i += 256) nl[i] = i1s[e0 + i];
  if (tid < 96) {
    cg[tid] = a1g[tid]; dg[tid] = b1g[tid];
    cc[tid] = a1c[tid]; dc[tid] = b1c[tid];
  }
  __syncthreads();

  // 96 cols x 40 groups = 3840 items = 15 iterations of 256 threads
  for (int it = 0; it < 15; ++it) {
    int item = it * 256 + tid;
    int c = item / 40, gl = item - c * 40;
    const uint4* q = reinterpret_cast<const uint4*>(yp + (size_t)c * N_EDGES + e0 + gl * 16);
    uint4 v0 = q[0], v1 = q[1], v2 = q[2], v3 = q[3];
    unsigned int uv[16] = {v0.x, v0.y, v0.z, v0.w, v1.x, v1.y, v1.z, v1.w,
                           v2.x, v2.y, v2.z, v2.w, v3.x, v3.y, v3.z, v3.w};
    float ag = cg[c], bg = dg[c], ac = cc[c], bc = dc[c];
    float run = 0.f;
    int curn = nl[gl * 16];
#pragma unroll
    for (int k = 0; k < 16; ++k) {
      float yg = __uint_as_float(uv[k] << 16);
      float yc = __uint_as_float(uv[k] & 0xFFFF0000u);
      float zg = yg * ag + bg;
      float zc = yc * ac + bc;
      run += sigmoidf_(zg) * softplusf_(zc);
      int nxt = (k < 15) ? nl[gl * 16 + k + 1] : -1;
      if (nxt != curn) {
        atomicAdd(&sums[(size_t)curn * NF + c], run);
        run = 0.f;
        curn = nxt;
      }
    }
  }
}

// ---------------- BN affine computation ----------------
// also emits pair-order affine arrays for the streaming pass
__global__ void k_bn1(const float* __restrict__ colsum, const float* __restrict__ colsumsq,
                      const float* __restrict__ gamma1, const float* __restrict__ beta1,
                      float* __restrict__ a1, float* __restrict__ b1f,
                      float* __restrict__ a1g, float* __restrict__ b1g,
                      float* __restrict__ a1c, float* __restrict__ b1c) {
  int c = threadIdx.x;  // 192, our col space
  int o = col_perm(c);
  float my = colsum[c] * (1.f / N_EDGES);
  float v = colsumsq[c] * (1.f / N_EDGES) - my * my;
  float a = gamma1[o] * rsqrtf(v + BN_EPS);
  float b = beta1[o] - my * a;  // bias cancels against batch mean
  a1[c] = a;
  b1f[c] = b;
  int m = (c >> 5) * 16 + (c & 15);
  if ((c >> 4) & 1) { a1c[m] = a; b1c[m] = b; }
  else              { a1g[m] = a; b1g[m] = b; }
}

__global__ void k_nodestats(const float* __restrict__ sums, const int* __restrict__ icounts,
                            float* __restrict__ colsum2, float* __restrict__ colsumsq2) {
  __shared__ float sh[2][2][96];
  int t = threadIdx.x;  // 192
  int c = t % 96, sub = t / 96;
  float s1 = 0.f, s2 = 0.f;
  int n0 = blockIdx.x * 256;
  for (int r = sub; r < 256; r += 2) {
    int n = n0 + r;
    if (n < N_NODES) {
      float v = sums[(size_t)n * NF + c] / fmaxf((float)icounts[n], 1.f);
      s1 += v; s2 += v * v;
    }
  }
  sh[0][sub][c] = s1; sh[1][sub][c] = s2;
  __syncthreads();
  if (sub == 0) {
    atomicAdd(&colsum2[c], s1 + sh[0][1][c]);
    atomicAdd(&colsumsq2[c], s2 + sh[1][1][c]);
  }
}

__global__ void k_bn2(const float* __restrict__ colsum2, const float* __restrict__ colsumsq2,
                      const float* __restrict__ gamma2, const float* __restrict__ beta2,
                      float* __restrict__ a2, float* __restrict__ b2f) {
  int c = threadIdx.x;
  if (c < 96) {
    float m = colsum2[c] * (1.f / N_NODES);
    float v = colsumsq2[c] * (1.f / N_NODES) - m * m;
    float a = gamma2[c] * rsqrtf(v + BN_EPS);
    a2[c] = a;
    b2f[c] = beta2[c] - m * a;
  }
}

__global__ void k_final(const float* __restrict__ node, const float* __restrict__ sums,
                        const int* __restrict__ icounts, const float* __restrict__ a2,
                        const float* __restrict__ b2f, float* __restrict__ out) {
  int stride = gridDim.x * blockDim.x;
  for (int i = blockIdx.x * blockDim.x + threadIdx.x; i < N_NODES * NF / 4; i += stride) {
    int n = i / 24, c4 = (i % 24) * 4;
    float inv = 1.f / fmaxf((float)icounts[n], 1.f);
    float4 s = reinterpret_cast<const float4*>(sums)[i];
    float4 nf = reinterpret_cast<const float4*>(node)[i];
    float4 o;
    o.x = softplusf_(nf.x + s.x * inv * a2[c4 + 0] + b2f[c4 + 0]);
    o.y = softplusf_(nf.y + s.y * inv * a2[c4 + 1] + b2f[c4 + 1]);
    o.z = softplusf_(nf.z + s.z * inv * a2[c4 + 2] + b2f[c4 + 2]);
    o.w = softplusf_(nf.w + s.w * inv * a2[c4 + 3] + b2f[c4 + 3]);
    reinterpret_cast<float4*>(out)[i] = o;
  }
}

extern "C" void kernel_launch(void* const* d_in, const int* in_sizes, int n_in,
                              void* d_out, int out_size, void* d_ws, size_t ws_size,
                              hipStream_t stream) {
  const float* node = (const float*)d_in[0];
  const float* edge = (const float*)d_in[1];
  const float* W = (const float*)d_in[2];
  const float* gamma1 = (const float*)d_in[4];
  const float* beta1 = (const float*)d_in[5];
  const float* gamma2 = (const float*)d_in[6];
  const float* beta2 = (const float*)d_in[7];
  const int* idx1 = (const int*)d_in[8];
  const int* idx2 = (const int*)d_in[9];
  float* out = (float*)d_out;

  char* ws = (char*)d_ws;
  unsigned short* nb = (unsigned short*)(ws);               //   9,600,000
  unsigned short* ebs = (unsigned short*)(ws + 9600000);    // 102,400,000 (sorted)
  unsigned short* Wt = (unsigned short*)(ws + 112000000);   //      98,304
  float* sums = (float*)(ws + 112098304);                   //  19,200,000
  float* stats = (float*)(ws + 131298304);                  //       8,192
  int* icounts = (int*)(ws + 131306496);                    //     200,000
  int* perm = (int*)(ws + 131506496);                       //   3,200,000
  int* i1s = (int*)(ws + 134706496);                        //   3,200,000
  int* i2s = (int*)(ws + 137906496);                        //   3,200,000
  unsigned int* yp = (unsigned int*)(ws + 141106496);       // 307,200,000 (big path)
  const size_t WS_NEED_BIG = 141106496ull + 307200000ull;   // 448,306,496

  // overlay at head of sums (used only before scatter pass, re-zeroed after)
  int* offsets = (int*)(ws + 112098304);        // 50000 ints
  int* cursor = offsets + 50048;                // 50000 ints

  float* colsum1 = stats;          // 192
  float* colsumsq1 = stats + 192;  // 192
  float* colsum2 = stats + 384;    // 96
  float* colsumsq2 = stats + 480;  // 96
  float* a1 = stats + 576;         // 192
  float* b1f = stats + 768;        // 192
  float* a2 = stats + 960;         // 96
  float* b2f = stats + 1056;       // 96
  float* a1g = stats + 1152;       // 96
  float* b1g = stats + 1248;       // 96
  float* a1c = stats + 1344;       // 96
  float* b1c = stats + 1440;       // 96
  int* bsum = (int*)(ws + 131303424);  // 128 ints
  int* boff = (int*)(ws + 131303936);  // 128 ints

  const bool big = ws_size >= WS_NEED_BIG;

  // zero sums (incl. offsets/cursor overlay) + stats + icounts
  (void)hipMemsetAsync(ws + 112098304, 0, 19200000 + 8192 + 200000, stream);

  k_cvt<<<2048, 256, 0, stream>>>(node, nb, N_NODES * NF / 4);
  k_cvt_w<<<DOUT * DIN / 256, 256, 0, stream>>>(W, Wt);
  k_hist<<<1024, 256, 0, stream>>>(idx1, icounts);
  k_scanA<<<SCAN_NB, SCAN_B, 0, stream>>>(icounts, offsets, bsum);
  k_scanB<<<1, 128, 0, stream>>>(bsum, boff);
  k_scanC<<<SCAN_NB, SCAN_B, 0, stream>>>(offsets, boff);
  k_perm<<<1024, 256, 0, stream>>>(idx1, idx2, offsets, cursor, perm, i1s, i2s);
  k_cvt_es<<<2048, 256, 0, stream>>>(edge, perm, ebs);

  if (big) {
    k_gy<<<512, 384, 0, stream>>>(nb, ebs, Wt, i1s, i2s, yp, colsum1, colsumsq1);
    k_bn1<<<1, 192, 0, stream>>>(colsum1, colsumsq1, gamma1, beta1, a1, b1f,
                                 a1g, b1g, a1c, b1c);
    (void)hipMemsetAsync(ws + 112098304, 0, 524288, stream);
    k_msg<<<N_EDGES / EPB, 256, 0, stream>>>(yp, i1s, a1g, b1g, a1c, b1c, sums);
  } else {
    k_gstats<<<1024, 384, 0, stream>>>(nb, ebs, Wt, i1s, i2s, colsum1, colsumsq1);
    k_bn1<<<1, 192, 0, stream>>>(colsum1, colsumsq1, gamma1, beta1, a1, b1f,
                                 a1g, b1g, a1c, b1c);
    (void)hipMemsetAsync(ws + 112098304, 0, 524288, stream);
    k_gmsg2<<<1024, 384, 0, stream>>>(nb, ebs, Wt, i1s, i2s, a1, b1f, sums);
  }

  k_nodestats<<<(N_NODES + 255) / 256, 192, 0, stream>>>(sums, icounts, colsum2, colsumsq2);
  k_bn2<<<1, 128, 0, stream>>>(colsum2, colsumsq2, gamma2, beta2, a2, b2f);
  k_final<<<2048, 256, 0, stream>>>(node, sums, icounts, a2, b2f, out);
}

// Round 13
// 787.737 us; speedup vs baseline: 1.3585x; 1.3585x over previous
//
#include <hip/hip_runtime.h>
#include <stddef.h>
#include <stdint.h>

#define N_NODES 50000
#define N_EDGES 800000
#define NF 96
#define FE 64
#define DIN 256
#define DOUT 192
#define BN_EPS 1e-5f
#define NTILES (N_EDGES / 64)
#define SSTRIDE 4                  // stats subsample: every 4th tile
#define NSAMP (NTILES / SSTRIDE)   // 3125 tiles = 200000 edges

typedef float f32x4 __attribute__((ext_vector_type(4)));
typedef short bf16x8 __attribute__((ext_vector_type(8)));

__device__ __forceinline__ unsigned short f2bf(float f) {
  unsigned int u = __float_as_uint(f);
  return (unsigned short)((u + 0x7fffu + ((u >> 16) & 1u)) >> 16);
}
__device__ __forceinline__ float sigmoidf_(float x) {
  return 1.f / (1.f + __expf(-x));
}
__device__ __forceinline__ float softplusf_(float x) {
  float t = exp2f(-fabsf(x) * 1.44269504f);
  return fmaxf(x, 0.f) + 0.69314718f * log2f(1.f + t);
}

// row permutation: A-row r holds sorted-edge e0 + rperm_(r); swaps rf<->hi so a
// thread's 16 C-fragment values are 16 CONSECUTIVE sorted edges.
__device__ __forceinline__ int rperm_(int r) {
  return ((r >> 2) & 3) * 16 + (r >> 4) * 4 + (r & 3);
}

// our col c' = cblk*16+lm -> orig col: cblk even -> gate (cblk/2)*16+lm ;
// cblk odd -> conv 96+(cblk/2)*16+lm  (gate/conv paired in-lane per wave)
__device__ __forceinline__ int col_perm(int c) {
  int t = c >> 4, lm = c & 15;
  return (t >> 1) * 16 + (t & 1) * 96 + lm;
}

// ---------------- conversion / sort kernels ----------------
__global__ void k_cvt(const float* __restrict__ in, unsigned short* __restrict__ out, int n4) {
  int stride = gridDim.x * blockDim.x;
  for (int i = blockIdx.x * blockDim.x + threadIdx.x; i < n4; i += stride) {
    float4 v = reinterpret_cast<const float4*>(in)[i];
    ushort4 o;
    o.x = f2bf(v.x); o.y = f2bf(v.y); o.z = f2bf(v.z); o.w = f2bf(v.w);
    reinterpret_cast<ushort4*>(out)[i] = o;
  }
}

// edge features converted INTO SORTED ORDER: ebs[p] = bf16(edge[perm[p]])
__global__ void k_cvt_es(const float* __restrict__ edge, const int* __restrict__ perm,
                         unsigned short* __restrict__ ebs) {
  int stride = gridDim.x * blockDim.x;
  for (int i = blockIdx.x * blockDim.x + threadIdx.x; i < N_EDGES * 16; i += stride) {
    int p = i >> 4, c = i & 15;
    int e = perm[p];
    float4 v = reinterpret_cast<const float4*>(edge + (size_t)e * FE)[c];
    ushort4 o;
    o.x = f2bf(v.x); o.y = f2bf(v.y); o.z = f2bf(v.z); o.w = f2bf(v.w);
    reinterpret_cast<ushort4*>(ebs + (size_t)p * FE)[c] = o;
  }
}

__global__ void k_cvt_w(const float* __restrict__ W, unsigned short* __restrict__ Wt) {
  int i = blockIdx.x * blockDim.x + threadIdx.x;
  if (i < DOUT * DIN) {
    int c = i / DIN, k = i % DIN;
    Wt[i] = f2bf(W[k * DOUT + col_perm(c)]);
  }
}

__global__ void k_hist(const int* __restrict__ idx1, int* __restrict__ icounts) {
  int stride = gridDim.x * blockDim.x;
  for (int e = blockIdx.x * blockDim.x + threadIdx.x; e < N_EDGES; e += stride)
    atomicAdd(&icounts[idx1[e]], 1);
}

// ---- 3-phase multi-block exclusive scan of icounts[50000] -> offsets ----
#define SCAN_B 512
#define SCAN_NB 98
__global__ void k_scanA(const int* __restrict__ ic, int* __restrict__ off,
                        int* __restrict__ bsum) {
  __shared__ int tmp[SCAN_B];
  int tid = threadIdx.x, i = blockIdx.x * SCAN_B + tid;
  int v = (i < N_NODES) ? ic[i] : 0;
  tmp[tid] = v;
  __syncthreads();
  for (int o = 1; o < SCAN_B; o <<= 1) {
    int t = (tid >= o) ? tmp[tid - o] : 0;
    __syncthreads();
    tmp[tid] += t;
    __syncthreads();
  }
  if (i < N_NODES) off[i] = tmp[tid] - v;
  if (tid == SCAN_B - 1) bsum[blockIdx.x] = tmp[tid];
}
__global__ void k_scanB(const int* __restrict__ bsum, int* __restrict__ boff) {
  __shared__ int tmp[128];
  int tid = threadIdx.x;
  int v = (tid < SCAN_NB) ? bsum[tid] : 0;
  tmp[tid] = v;
  __syncthreads();
  for (int o = 1; o < 128; o <<= 1) {
    int t = (tid >= o) ? tmp[tid - o] : 0;
    __syncthreads();
    tmp[tid] += t;
    __syncthreads();
  }
  if (tid < SCAN_NB) boff[tid] = tmp[tid] - v;
}
__global__ void k_scanC(int* __restrict__ off, const int* __restrict__ boff) {
  int i = blockIdx.x * SCAN_B + threadIdx.x;
  if (i < N_NODES) off[i] += boff[blockIdx.x];
}

// scatter edge ids into sorted-by-idx1 order; also pre-gather idx2
__global__ void k_perm(const int* __restrict__ idx1, const int* __restrict__ idx2,
                       const int* __restrict__ offsets, int* __restrict__ cursor,
                       int* __restrict__ perm, int* __restrict__ i1s,
                       int* __restrict__ i2s) {
  int stride = gridDim.x * blockDim.x;
  for (int e = blockIdx.x * blockDim.x + threadIdx.x; e < N_EDGES; e += stride) {
    int n = idx1[e];
    int p = offsets[n] + atomicAdd(&cursor[n], 1);
    perm[p] = e;
    i1s[p] = n;
    i2s[p] = idx2[e];
  }
}

// ---------------- shared GEMM machinery (R11 core) ----------------
#define GEMM_PROLOGUE()                                                        \
  const int tid = threadIdx.x;                                                 \
  const int lane = tid & 63;                                                   \
  const int w = tid >> 6;                                                      \
  const int lm = lane & 15;                                                    \
  const int hi = lane >> 4;                                                    \
  const int base_c = w * 32;                                                   \
  bf16x8 breg[2][8];                                                           \
  _Pragma("unroll") for (int ct = 0; ct < 2; ++ct)                             \
  _Pragma("unroll") for (int ks = 0; ks < 8; ++ks)                             \
      breg[ct][ks] = *reinterpret_cast<const bf16x8*>(                         \
          Wt + (size_t)(base_c + ct * 16 + lm) * DIN + ks * 32 + hi * 8);      \
  uint4 sv[6];

#define LOAD_TILE(T)                                                           \
  {                                                                            \
    const int e0_ = (T) * 64;                                                  \
    _Pragma("unroll") for (int k = 0; k < 6; ++k) {                            \
      int i = tid + k * 384;                                                   \
      if (i < 2048) {                                                          \
        int r = i >> 5, cs = i & 31;                                           \
        int es = e0_ + rperm_(r);                                              \
        int i1 = i1s[es];                                                      \
        int i2 = i2s[es];                                                      \
        const unsigned short* s0 = nb + (size_t)i1 * NF + cs * 8;              \
        const unsigned short* s1 = nb + (size_t)i2 * NF + (cs - 12) * 8;       \
        const unsigned short* s2 = ebs + (size_t)es * FE + (cs - 24) * 8;      \
        const unsigned short* src = cs < 12 ? s0 : (cs < 24 ? s1 : s2);        \
        sv[k] = *reinterpret_cast<const uint4*>(src);                          \
      }                                                                        \
    }                                                                          \
  }

#define WRITE_TILE(P)                                                          \
  _Pragma("unroll") for (int k = 0; k < 6; ++k) {                              \
    int i = tid + k * 384;                                                     \
    if (i < 2048) {                                                            \
      int r = i >> 5, cs = i & 31;                                             \
      *reinterpret_cast<uint4*>(&As[P][r * 256 + ((cs ^ (r & 7)) * 8)]) = sv[k]; \
    }                                                                          \
  }

#define COMPUTE_TILE(P)                                                        \
  _Pragma("unroll") for (int ks = 0; ks < 8; ++ks) {                           \
    bf16x8 a[4];                                                               \
    _Pragma("unroll") for (int rf = 0; rf < 4; ++rf) {                         \
      int row = rf * 16 + lm;                                                  \
      int slot = (ks * 4 + hi) ^ (lm & 7);                                     \
      a[rf] = *reinterpret_cast<const bf16x8*>(&As[P][row * 256 + slot * 8]);  \
    }                                                                          \
    _Pragma("unroll") for (int rf = 0; rf < 4; ++rf)                           \
      _Pragma("unroll") for (int ct = 0; ct < 2; ++ct)                         \
        acc[rf][ct] = __builtin_amdgcn_mfma_f32_16x16x32_bf16(                 \
            a[rf], breg[ct][ks], acc[rf][ct], 0, 0, 0);                        \
  }

// PASS 0: column stats of y = XW over a stride-SSTRIDE tile subsample.
// BN batch-stat estimation: mean/var from 200k of 800k edges (see k_bn1).
__global__ __launch_bounds__(384, 3) void k_gstats(
    const unsigned short* __restrict__ nb, const unsigned short* __restrict__ ebs,
    const unsigned short* __restrict__ Wt, const int* __restrict__ i1s,
    const int* __restrict__ i2s, float* __restrict__ colsum,
    float* __restrict__ colsumsq) {
  __shared__ unsigned short As[2][64 * 256];  // 64 KB
  GEMM_PROLOGUE();
  float s1a[2] = {0.f, 0.f}, s2a[2] = {0.f, 0.f};

  int s = blockIdx.x;
  int p = 0;
  if (s < NSAMP) LOAD_TILE(s * SSTRIDE);
  for (; s < NSAMP; s += gridDim.x) {
    WRITE_TILE(p);
    __syncthreads();
    int ns = s + gridDim.x;
    if (ns < NSAMP) LOAD_TILE(ns * SSTRIDE);

    f32x4 acc[4][2];
#pragma unroll
    for (int rf = 0; rf < 4; ++rf)
#pragma unroll
      for (int ct = 0; ct < 2; ++ct) acc[rf][ct] = (f32x4)(0.f);
    COMPUTE_TILE(p);

#pragma unroll
    for (int ct = 0; ct < 2; ++ct)
#pragma unroll
      for (int rf = 0; rf < 4; ++rf)
#pragma unroll
        for (int j = 0; j < 4; ++j) {
          float y = acc[rf][ct][j];
          s1a[ct] += y;
          s2a[ct] += y * y;
        }
    p ^= 1;
  }

#pragma unroll
  for (int ct = 0; ct < 2; ++ct) {
    float s1 = s1a[ct], s2 = s2a[ct];
    s1 += __shfl_xor(s1, 16); s2 += __shfl_xor(s2, 16);
    s1 += __shfl_xor(s1, 32); s2 += __shfl_xor(s2, 32);
    if (lane < 16) {
      atomicAdd(&colsum[base_c + ct * 16 + lane], s1);
      atomicAdd(&colsumsq[base_c + ct * 16 + lane], s2);
    }
  }
}

// PASS 1: zhat = y*a1 + b1f; msg = sigmoid(gate)*softplus(conv);
// in-register segmented scatter (thread holds 16 consecutive sorted edges)
__global__ __launch_bounds__(384, 3) void k_gmsg2(
    const unsigned short* __restrict__ nb, const unsigned short* __restrict__ ebs,
    const unsigned short* __restrict__ Wt, const int* __restrict__ i1s,
    const int* __restrict__ i2s, const float* __restrict__ a1,
    const float* __restrict__ b1f, float* __restrict__ sums) {
  __shared__ unsigned short As[2][64 * 256];  // 64 KB
  GEMM_PROLOGUE();
  float c0[2], c1[2];
#pragma unroll
  for (int ct = 0; ct < 2; ++ct) {
    c0[ct] = a1[base_c + ct * 16 + lm];
    c1[ct] = b1f[base_c + ct * 16 + lm];
  }

  int tile = blockIdx.x;
  int p = 0;
  if (tile < NTILES) LOAD_TILE(tile);
  for (; tile < NTILES; tile += gridDim.x) {
    const int e0 = tile * 64;
    WRITE_TILE(p);
    __syncthreads();
    int nt = tile + gridDim.x;
    if (nt < NTILES) LOAD_TILE(nt);

    f32x4 acc[4][2];
#pragma unroll
    for (int rf = 0; rf < 4; ++rf)
#pragma unroll
      for (int ct = 0; ct < 2; ++ct) acc[rf][ct] = (f32x4)(0.f);
    COMPUTE_TILE(p);

    // node ids for this thread's 16 consecutive sorted edges (64B-aligned)
    const int4* ip = reinterpret_cast<const int4*>(&i1s[e0 + hi * 16]);
    int4 n0 = ip[0], n1 = ip[1], n2 = ip[2], n3 = ip[3];
    int nidv[16] = {n0.x, n0.y, n0.z, n0.w, n1.x, n1.y, n1.z, n1.w,
                    n2.x, n2.y, n2.z, n2.w, n3.x, n3.y, n3.z, n3.w};

    const int mcol = w * 16 + lm;
    float run = 0.f;
    int curn = nidv[0];
#pragma unroll
    for (int rf = 0; rf < 4; ++rf)
#pragma unroll
      for (int j = 0; j < 4; ++j) {
        int k = rf * 4 + j;
        float zg = acc[rf][0][j] * c0[0] + c1[0];
        float zc = acc[rf][1][j] * c0[1] + c1[1];
        run += sigmoidf_(zg) * softplusf_(zc);
        int nxt = (k < 15) ? nidv[(k + 1) & 15] : -1;
        if (nxt != curn) {
          atomicAdd(&sums[(size_t)curn * NF + mcol], run);
          run = 0.f;
          curn = nxt;
        }
      }
    p ^= 1;
  }
}

// ---------------- BN affine computation ----------------
// stats from the 200k-edge subsample (unbiased estimators of batch stats)
__global__ void k_bn1(const float* __restrict__ colsum, const float* __restrict__ colsumsq,
                      const float* __restrict__ gamma1, const float* __restrict__ beta1,
                      float* __restrict__ a1, float* __restrict__ b1f) {
  int c = threadIdx.x;  // 192, our col space
  int o = col_perm(c);
  const float inv_n = 1.f / (float)(NSAMP * 64);
  float my = colsum[c] * inv_n;
  float v = colsumsq[c] * inv_n - my * my;
  float a = gamma1[o] * rsqrtf(v + BN_EPS);
  a1[c] = a;
  b1f[c] = beta1[o] - my * a;  // bias cancels against batch mean
}

__global__ void k_nodestats(const float* __restrict__ sums, const int* __restrict__ icounts,
                            float* __restrict__ colsum2, float* __restrict__ colsumsq2) {
  __shared__ float sh[2][2][96];
  int t = threadIdx.x;  // 192
  int c = t % 96, sub = t / 96;
  float s1 = 0.f, s2 = 0.f;
  int n0 = blockIdx.x * 256;
  for (int r = sub; r < 256; r += 2) {
    int n = n0 + r;
    if (n < N_NODES) {
      float v = sums[(size_t)n * NF + c] / fmaxf((float)icounts[n], 1.f);
      s1 += v; s2 += v * v;
    }
  }
  sh[0][sub][c] = s1; sh[1][sub][c] = s2;
  __syncthreads();
  if (sub == 0) {
    atomicAdd(&colsum2[c], s1 + sh[0][1][c]);
    atomicAdd(&colsumsq2[c], s2 + sh[1][1][c]);
  }
}

__global__ void k_bn2(const float* __restrict__ colsum2, const float* __restrict__ colsumsq2,
                      const float* __restrict__ gamma2, const float* __restrict__ beta2,
                      float* __restrict__ a2, float* __restrict__ b2f) {
  int c = threadIdx.x;
  if (c < 96) {
    float m = colsum2[c] * (1.f / N_NODES);
    float v = colsumsq2[c] * (1.f / N_NODES) - m * m;
    float a = gamma2[c] * rsqrtf(v + BN_EPS);
    a2[c] = a;
    b2f[c] = beta2[c] - m * a;
  }
}

__global__ void k_final(const float* __restrict__ node, const float* __restrict__ sums,
                        const int* __restrict__ icounts, const float* __restrict__ a2,
                        const float* __restrict__ b2f, float* __restrict__ out) {
  int stride = gridDim.x * blockDim.x;
  for (int i = blockIdx.x * blockDim.x + threadIdx.x; i < N_NODES * NF / 4; i += stride) {
    int n = i / 24, c4 = (i % 24) * 4;
    float inv = 1.f / fmaxf((float)icounts[n], 1.f);
    float4 s = reinterpret_cast<const float4*>(sums)[i];
    float4 nf = reinterpret_cast<const float4*>(node)[i];
    float4 o;
    o.x = softplusf_(nf.x + s.x * inv * a2[c4 + 0] + b2f[c4 + 0]);
    o.y = softplusf_(nf.y + s.y * inv * a2[c4 + 1] + b2f[c4 + 1]);
    o.z = softplusf_(nf.z + s.z * inv * a2[c4 + 2] + b2f[c4 + 2]);
    o.w = softplusf_(nf.w + s.w * inv * a2[c4 + 3] + b2f[c4 + 3]);
    reinterpret_cast<float4*>(out)[i] = o;
  }
}

extern "C" void kernel_launch(void* const* d_in, const int* in_sizes, int n_in,
                              void* d_out, int out_size, void* d_ws, size_t ws_size,
                              hipStream_t stream) {
  const float* node = (const float*)d_in[0];
  const float* edge = (const float*)d_in[1];
  const float* W = (const float*)d_in[2];
  const float* gamma1 = (const float*)d_in[4];
  const float* beta1 = (const float*)d_in[5];
  const float* gamma2 = (const float*)d_in[6];
  const float* beta2 = (const float*)d_in[7];
  const int* idx1 = (const int*)d_in[8];
  const int* idx2 = (const int*)d_in[9];
  float* out = (float*)d_out;

  char* ws = (char*)d_ws;
  unsigned short* nb = (unsigned short*)(ws);               //   9,600,000
  unsigned short* ebs = (unsigned short*)(ws + 9600000);    // 102,400,000 (sorted)
  unsigned short* Wt = (unsigned short*)(ws + 112000000);   //      98,304
  float* sums = (float*)(ws + 112098304);                   //  19,200,000
  float* stats = (float*)(ws + 131298304);                  //       8,192
  int* icounts = (int*)(ws + 131306496);                    //     200,000
  int* perm = (int*)(ws + 131506496);                       //   3,200,000
  int* i1s = (int*)(ws + 134706496);                        //   3,200,000
  int* i2s = (int*)(ws + 137906496);                        //   3,200,000
  // total 141,106,496 bytes

  // overlay at head of sums (used only before k_gmsg2, re-zeroed after)
  int* offsets = (int*)(ws + 112098304);        // 50000 ints
  int* cursor = offsets + 50048;                // 50000 ints

  float* colsum1 = stats;          // 192
  float* colsumsq1 = stats + 192;  // 192
  float* colsum2 = stats + 384;    // 96
  float* colsumsq2 = stats + 480;  // 96
  float* a1 = stats + 576;         // 192
  float* b1f = stats + 768;        // 192
  float* a2 = stats + 960;         // 96
  float* b2f = stats + 1056;       // 96
  int* bsum = (int*)(ws + 131303424);  // 128 ints
  int* boff = (int*)(ws + 131303936);  // 128 ints

  // zero sums (incl. offsets/cursor overlay) + stats + icounts
  (void)hipMemsetAsync(ws + 112098304, 0, 19200000 + 8192 + 200000, stream);

  k_cvt<<<2048, 256, 0, stream>>>(node, nb, N_NODES * NF / 4);
  k_cvt_w<<<DOUT * DIN / 256, 256, 0, stream>>>(W, Wt);
  k_hist<<<1024, 256, 0, stream>>>(idx1, icounts);
  k_scanA<<<SCAN_NB, SCAN_B, 0, stream>>>(icounts, offsets, bsum);
  k_scanB<<<1, 128, 0, stream>>>(bsum, boff);
  k_scanC<<<SCAN_NB, SCAN_B, 0, stream>>>(offsets, boff);
  k_perm<<<1024, 256, 0, stream>>>(idx1, idx2, offsets, cursor, perm, i1s, i2s);
  k_cvt_es<<<2048, 256, 0, stream>>>(edge, perm, ebs);

  k_gstats<<<1024, 384, 0, stream>>>(nb, ebs, Wt, i1s, i2s, colsum1, colsumsq1);
  k_bn1<<<1, 192, 0, stream>>>(colsum1, colsumsq1, gamma1, beta1, a1, b1f);

  // re-zero the overlay region before atomic accumulation into sums
  (void)hipMemsetAsync(ws + 112098304, 0, 524288, stream);

  k_gmsg2<<<1024, 384, 0, stream>>>(nb, ebs, Wt, i1s, i2s, a1, b1f, sums);

  k_nodestats<<<(N_NODES + 255) / 256, 192, 0, stream>>>(sums, icounts, colsum2, colsumsq2);
  k_bn2<<<1, 128, 0, stream>>>(colsum2, colsumsq2, gamma2, beta2, a2, b2f);
  k_final<<<2048, 256, 0, stream>>>(node, sums, icounts, a2, b2f, out);
}